// Round 1
// baseline (837.341 us; speedup 1.0000x reference)
//
#include <hip/hip_runtime.h>
#include <hip/hip_bf16.h>
#include <math.h>

#define NP   19000      // NUM_PROTEINS
#define ND   1024       // NUM_DRUGS
#define CHN  256        // IN_CH == EMBED
#define ESG  1500000    // E_SG
#define NSG  800000     // N_SG
#define BDD  4096       // B_DD

// ---------------------------------------------------------------- utilities
static __device__ __forceinline__ int lower_bound_dev(const int* __restrict__ arr, int n, int val) {
    int lo = 0, hi = n;
    while (lo < hi) {
        int mid = (lo + hi) >> 1;
        if (arr[mid] < val) lo = mid + 1; else hi = mid;
    }
    return lo;
}

// ---------------------------------------------------------------- degree
__global__ void deg_kernel(const int* __restrict__ dst, int* __restrict__ deg) {
    int e = blockIdx.x * blockDim.x + threadIdx.x;
    if (e < ESG) atomicAdd(&deg[dst[e]], 1);
}

__global__ void dinv_kernel(const int* __restrict__ deg, float* __restrict__ dinv) {
    int i = blockIdx.x * blockDim.x + threadIdx.x;
    if (i < NP) dinv[i] = 1.0f / sqrtf((float)deg[i] + 1.0f);
}

// single-block exclusive scan of degree -> row_ptr, also seeds cursor
__global__ void scan_kernel(const int* __restrict__ deg, int* __restrict__ row_ptr,
                            int* __restrict__ cursor) {
    const int T = 256;
    const int PER = (NP + T - 1) / T;   // 75
    __shared__ int totals[T];
    __shared__ int excl[T + 1];
    int t = threadIdx.x;
    int base = t * PER;
    int local = 0;
    for (int i = 0; i < PER; i++) {
        int idx = base + i;
        if (idx < NP) local += deg[idx];
    }
    totals[t] = local;
    __syncthreads();
    if (t == 0) {
        int r = 0;
        for (int i = 0; i < T; i++) { excl[i] = r; r += totals[i]; }
        excl[T] = r;
    }
    __syncthreads();
    int run = excl[t];
    for (int i = 0; i < PER; i++) {
        int idx = base + i;
        if (idx < NP) {
            row_ptr[idx] = run;
            cursor[idx]  = run;
            run += deg[idx];
        }
    }
    if (t == 0) row_ptr[NP] = excl[T];
}

__global__ void fill_kernel(const int* __restrict__ src, const int* __restrict__ dst,
                            const float* __restrict__ dinv, int* __restrict__ cursor,
                            int* __restrict__ csr_src, float* __restrict__ csr_w) {
    int e = blockIdx.x * blockDim.x + threadIdx.x;
    if (e >= ESG) return;
    int s = src[e], d = dst[e];
    int pos = atomicAdd(&cursor[d], 1);
    csr_src[pos] = s;
    csr_w[pos]   = dinv[s] * dinv[d];
}

// ---------------------------------------------------------------- fp32 GEMM
// C[M,256] = A[M,256] @ B[256,256]; 64x64 tile, 4x4 per thread, 256 threads.
__global__ __launch_bounds__(256) void gemm_kernel(const float* __restrict__ A,
                                                   const float* __restrict__ B,
                                                   float* __restrict__ C, int M) {
    __shared__ float As[16][68];   // transposed: As[k][m], pad to 68 for alignment
    __shared__ float Bs[16][68];   // Bs[k][n]
    int tid = threadIdx.x;
    int m0 = blockIdx.x * 64;
    int n0 = blockIdx.y * 64;
    int tx = tid & 15;             // -> n quad
    int ty = tid >> 4;             // -> m quad
    int ar = tid >> 2;             // A load: row within tile (0..63)
    int ak = (tid & 3) << 2;       // A load: k quad (0,4,8,12)
    int bk = tid >> 4;             // B load: k row (0..15)
    int bn = (tid & 15) << 2;      // B load: n quad
    float acc[4][4] = {};
    for (int k0 = 0; k0 < 256; k0 += 16) {
        float4 av = make_float4(0.f, 0.f, 0.f, 0.f);
        int arow = m0 + ar;
        if (arow < M) av = *(const float4*)(A + (size_t)arow * 256 + k0 + ak);
        As[ak + 0][ar] = av.x; As[ak + 1][ar] = av.y;
        As[ak + 2][ar] = av.z; As[ak + 3][ar] = av.w;
        float4 bv = *(const float4*)(B + (size_t)(k0 + bk) * 256 + n0 + bn);
        *(float4*)&Bs[bk][bn] = bv;
        __syncthreads();
#pragma unroll
        for (int kk = 0; kk < 16; kk++) {
            float4 a = *(const float4*)&As[kk][ty << 2];
            float4 b = *(const float4*)&Bs[kk][tx << 2];
            acc[0][0] += a.x * b.x; acc[0][1] += a.x * b.y; acc[0][2] += a.x * b.z; acc[0][3] += a.x * b.w;
            acc[1][0] += a.y * b.x; acc[1][1] += a.y * b.y; acc[1][2] += a.y * b.z; acc[1][3] += a.y * b.w;
            acc[2][0] += a.z * b.x; acc[2][1] += a.z * b.y; acc[2][2] += a.z * b.z; acc[2][3] += a.z * b.w;
            acc[3][0] += a.w * b.x; acc[3][1] += a.w * b.y; acc[3][2] += a.w * b.z; acc[3][3] += a.w * b.w;
        }
        __syncthreads();
    }
#pragma unroll
    for (int i = 0; i < 4; i++) {
        int row = m0 + (ty << 2) + i;
        if (row < M) {
            float4 o = make_float4(acc[i][0], acc[i][1], acc[i][2], acc[i][3]);
            *(float4*)(C + (size_t)row * 256 + n0 + (tx << 2)) = o;
        }
    }
}

// ---------------------------------------------------------------- SpMM (row per block)
// out[row][ch] = act( sum_e w_e * hw[src_e][ch] + hw[row][ch]*dinv[row]^2 + bias[ch] (+ residual) )
__global__ __launch_bounds__(256) void spmm_kernel(const float* __restrict__ hw,
                                                   const int* __restrict__ row_ptr,
                                                   const int* __restrict__ csr_src,
                                                   const float* __restrict__ csr_w,
                                                   const float* __restrict__ dinv,
                                                   const float* __restrict__ bias,
                                                   const float* __restrict__ residual,
                                                   float* __restrict__ out, int do_relu) {
    int row = blockIdx.x;
    int ch  = threadIdx.x;
    int lo = row_ptr[row], hi = row_ptr[row + 1];
    __shared__ int   s_src[256];
    __shared__ float s_w[256];
    float acc = 0.f;
    for (int base = lo; base < hi; base += 256) {
        int i = base + ch;
        if (i < hi) { s_src[ch] = csr_src[i]; s_w[ch] = csr_w[i]; }
        __syncthreads();
        int cnt = min(256, hi - base);
#pragma unroll 4
        for (int j = 0; j < cnt; j++) {
            acc += s_w[j] * hw[(size_t)s_src[j] * 256 + ch];
        }
        __syncthreads();
    }
    float dv = dinv[row];
    acc += hw[(size_t)row * 256 + ch] * dv * dv + bias[ch];
    if (residual) acc += residual[(size_t)row * 256 + ch];
    if (do_relu) acc = fmaxf(acc, 0.f);
    out[(size_t)row * 256 + ch] = acc;
}

// ---------------------------------------------------------------- pooling (block per drug)
__global__ __launch_bounds__(256) void pool_kernel(const float* __restrict__ h2,
                                                   const int* __restrict__ sg_nodes,
                                                   const int* __restrict__ sg_idx,
                                                   float* __restrict__ drug_emb) {
    int d  = blockIdx.x;
    int ch = threadIdx.x;
    __shared__ int sh_lo, sh_hi;
    if (ch == 0) sh_lo = lower_bound_dev(sg_idx, NSG, d);
    if (ch == 1) sh_hi = lower_bound_dev(sg_idx, NSG, d + 1);
    __syncthreads();
    int lo = sh_lo, hi = sh_hi;
    __shared__ int nodes_s[256];
    float acc = 0.f;
    for (int base = lo; base < hi; base += 256) {
        int i = base + ch;
        nodes_s[ch] = (i < hi) ? sg_nodes[i] : 0;
        __syncthreads();
        int cnt = min(256, hi - base);
#pragma unroll 4
        for (int j = 0; j < cnt; j++) {
            acc += h2[(size_t)nodes_s[j] * 256 + ch];
        }
        __syncthreads();
    }
    float c = (float)max(hi - lo, 1);
    drug_emb[(size_t)d * 256 + ch] = acc / c;
}

// ---------------------------------------------------------------- dot head (wave per pair)
__global__ __launch_bounds__(256) void dot_kernel(const float* __restrict__ drug_emb,
                                                  const int* __restrict__ ddb,
                                                  float* __restrict__ out) {
    int wave = threadIdx.x >> 6;
    int lane = threadIdx.x & 63;
    int p = blockIdx.x * 4 + wave;
    if (p >= BDD) return;
    int a = ddb[p];
    int b = ddb[BDD + p];
    const float4* ea = (const float4*)(drug_emb + (size_t)a * 256);
    const float4* eb = (const float4*)(drug_emb + (size_t)b * 256);
    float4 va = ea[lane];
    float4 vb = eb[lane];
    float s = va.x * vb.x + va.y * vb.y + va.z * vb.z + va.w * vb.w;
#pragma unroll
    for (int off = 32; off > 0; off >>= 1) s += __shfl_down(s, off, 64);
    if (lane == 0) out[p] = s;
}

// ---------------------------------------------------------------- launcher
extern "C" void kernel_launch(void* const* d_in, const int* in_sizes, int n_in,
                              void* d_out, int out_size, void* d_ws, size_t ws_size,
                              hipStream_t stream) {
    const float* x        = (const float*)d_in[0];
    const int*   ddb      = (const int*)d_in[1];
    // d_in[2] edge_attr, d_in[3] edge_cell_lines: unused by reference
    const int*   sg_edge  = (const int*)d_in[4];   // [2, ESG]: src then dst
    const int*   sg_nodes = (const int*)d_in[5];
    const int*   sg_idx   = (const int*)d_in[6];
    const float* W1       = (const float*)d_in[7];
    const float* b1       = (const float*)d_in[8];
    const float* W2       = (const float*)d_in[9];
    const float* b2       = (const float*)d_in[10];
    float* out = (float*)d_out;

    char* ws = (char*)d_ws;
    size_t off = 0;
    auto alloc = [&](size_t bytes) -> void* {
        void* p = ws + off;
        off = (off + bytes + 255) & ~(size_t)255;
        return p;
    };
    int*   deg      = (int*)alloc(NP * sizeof(int));
    float* dinv     = (float*)alloc(NP * sizeof(float));
    int*   row_ptr  = (int*)alloc((NP + 1) * sizeof(int));
    int*   cursor   = (int*)alloc(NP * sizeof(int));
    int*   csr_src  = (int*)alloc((size_t)ESG * sizeof(int));
    float* csr_w    = (float*)alloc((size_t)ESG * sizeof(float));
    float* hwbuf    = (float*)alloc((size_t)NP * CHN * sizeof(float));
    float* h1       = (float*)alloc((size_t)NP * CHN * sizeof(float));
    float* h2       = (float*)alloc((size_t)NP * CHN * sizeof(float));
    float* drug_emb = (float*)alloc((size_t)ND * CHN * sizeof(float));

    const int* src = sg_edge;
    const int* dst = sg_edge + ESG;

    hipMemsetAsync(deg, 0, NP * sizeof(int), stream);
    deg_kernel<<<(ESG + 255) / 256, 256, 0, stream>>>(dst, deg);
    dinv_kernel<<<(NP + 255) / 256, 256, 0, stream>>>(deg, dinv);
    scan_kernel<<<1, 256, 0, stream>>>(deg, row_ptr, cursor);
    fill_kernel<<<(ESG + 255) / 256, 256, 0, stream>>>(src, dst, dinv, cursor, csr_src, csr_w);

    dim3 ggrid((NP + 63) / 64, 4);
    // layer 1: hw = x @ W1 ; h1 = relu(agg + hw*self_norm + b1)
    gemm_kernel<<<ggrid, 256, 0, stream>>>(x, W1, hwbuf, NP);
    spmm_kernel<<<NP, 256, 0, stream>>>(hwbuf, row_ptr, csr_src, csr_w, dinv, b1,
                                        nullptr, h1, 1);
    // layer 2: hw = h1 @ W2 ; h2 = (agg + hw*self_norm + b2) + h1
    gemm_kernel<<<ggrid, 256, 0, stream>>>(h1, W2, hwbuf, NP);
    spmm_kernel<<<NP, 256, 0, stream>>>(hwbuf, row_ptr, csr_src, csr_w, dinv, b2,
                                        h1, h2, 0);
    // scatter-mean pooling into drug embeddings
    pool_kernel<<<ND, 256, 0, stream>>>(h2, sg_nodes, sg_idx, drug_emb);
    // dot-product head
    dot_kernel<<<(BDD + 3) / 4, 256, 0, stream>>>(drug_emb, ddb, out);
}